// Round 5
// baseline (359.231 us; speedup 1.0000x reference)
//
#include <hip/hip_runtime.h>
#include <hip/hip_bf16.h>

using bf16x8 = __attribute__((ext_vector_type(8))) short;
using f32x4  = __attribute__((ext_vector_type(4))) float;

__device__ __forceinline__ unsigned short f32_to_bf16(float f) {
  unsigned u = __float_as_uint(f);
  u += 0x7FFFu + ((u >> 16) & 1u);   // RNE
  return (unsigned short)(u >> 16);
}
__device__ __forceinline__ unsigned pack2(float lo, float hi) {
  __hip_bfloat162 h = __float22bfloat162_rn(make_float2(lo, hi)); // v_cvt_pk path
  return *reinterpret_cast<unsigned*>(&h);
}
__device__ __forceinline__ void gload_lds16(const void* g, void* l) {
  __builtin_amdgcn_global_load_lds(
      (const __attribute__((address_space(1))) unsigned int*)g,
      (__attribute__((address_space(3))) unsigned int*)l, 16, 0, 0);
}

// ---------------- elementwise casts ----------------
__global__ void cast_bf16_kernel(const float* __restrict__ src,
                                 unsigned short* __restrict__ dst) {
  int i = blockIdx.x * blockDim.x + threadIdx.x;
  float4 v = reinterpret_cast<const float4*>(src)[i];
  ushort4 o;
  o.x = f32_to_bf16(v.x); o.y = f32_to_bf16(v.y);
  o.z = f32_to_bf16(v.z); o.w = f32_to_bf16(v.w);
  reinterpret_cast<ushort4*>(dst)[i] = o;
}
__global__ void cast2_bf16_kernel(const float* __restrict__ s0, unsigned short* __restrict__ d0,
                                  int n0v, const float* __restrict__ s1,
                                  unsigned short* __restrict__ d1) {
  int i = blockIdx.x * blockDim.x + threadIdx.x;
  const float* s; unsigned short* d; int j;
  if (i < n0v) { s = s0; d = d0; j = i; } else { s = s1; d = d1; j = i - n0v; }
  float4 v = reinterpret_cast<const float4*>(s)[j];
  ushort4 o;
  o.x = f32_to_bf16(v.x); o.y = f32_to_bf16(v.y);
  o.z = f32_to_bf16(v.z); o.w = f32_to_bf16(v.w);
  reinterpret_cast<ushort4*>(d)[j] = o;
}

// ---------------- GEMM: C[M,N] = A[M,K] * W[N,K]^T  (m97 structure) ----------------
__global__ __launch_bounds__(256) void gemm_bt_kernel(
    const unsigned short* __restrict__ A, const unsigned short* __restrict__ Bw,
    float* __restrict__ C, int M, int N, int K) {
  __shared__ unsigned short As[128 * 32];
  __shared__ unsigned short Bs[128 * 32];
  const int tid = threadIdx.x;
  const int bn = blockIdx.x, bm = blockIdx.y;
  const int w = tid >> 6, lane = tid & 63;
  const int wr = w >> 1, wc = w & 1;
  const int lr = lane & 15, lg = lane >> 4;
  const int srow = lane >> 2;
  const int scolb = (lane & 3) * 16;
  f32x4 acc[4][4] = {};
  for (int k0 = 0; k0 < K; k0 += 32) {
    __syncthreads();
#pragma unroll
    for (int i = 0; i < 2; ++i) {
      int row = w * 32 + i * 16 + srow;
      gload_lds16((const char*)A + ((size_t)(bm * 128 + row) * K + k0) * 2 + scolb,
                  (char*)As + w * 2048 + i * 1024);
      gload_lds16((const char*)Bw + ((size_t)(bn * 128 + row) * K + k0) * 2 + scolb,
                  (char*)Bs + w * 2048 + i * 1024);
    }
    __syncthreads();
    bf16x8 af[4], bfr[4];
#pragma unroll
    for (int i = 0; i < 4; ++i)
      af[i] = *reinterpret_cast<const bf16x8*>((char*)As + (wr * 64 + i * 16 + lr) * 64 + lg * 16);
#pragma unroll
    for (int j = 0; j < 4; ++j)
      bfr[j] = *reinterpret_cast<const bf16x8*>((char*)Bs + (wc * 64 + j * 16 + lr) * 64 + lg * 16);
#pragma unroll
    for (int i = 0; i < 4; ++i)
#pragma unroll
      for (int j = 0; j < 4; ++j)
        acc[i][j] = __builtin_amdgcn_mfma_f32_16x16x32_bf16(af[i], bfr[j], acc[i][j], 0, 0, 0);
  }
#pragma unroll
  for (int i = 0; i < 4; ++i) {
    const int m = bm * 128 + wr * 64 + i * 16 + lg * 4;
#pragma unroll
    for (int j = 0; j < 4; ++j) {
      const int n = bn * 128 + wc * 64 + j * 16 + lr;
#pragma unroll
      for (int r = 0; r < 4; ++r)
        C[(size_t)(m + r) * N + n] = acc[i][j][r];
    }
  }
}

// ---------------- RoPE on K + keys output (reads fused XQKV, ld=3072) ----------------
__global__ void rope_k_kernel(const float* __restrict__ xqkv, const float* __restrict__ fc,
                              const float* __restrict__ fs, unsigned short* __restrict__ kbf,
                              float* __restrict__ keys) {
  int idx = blockIdx.x * 256 + threadIdx.x;   // pair index over (b,l,kv,i)
  int i = idx & 63;
  int kvh = (idx >> 6) & 3;
  int l = (idx >> 8) & 2047;
  int b = idx >> 19;
  float2 t = reinterpret_cast<const float2*>(xqkv)[(size_t)(b * 2048 + l) * 1536 + 1024 + kvh * 64 + i];
  float c = fc[l * 64 + i], s = fs[l * 64 + i];
  float r0 = t.x * c - t.y * s;
  float r1 = t.x * s + t.y * c;
  int kidx = ((b * 4 + kvh) * 2048 + l) * 64 + i;
  ushort2 o; o.x = f32_to_bf16(r0); o.y = f32_to_bf16(r1);
  reinterpret_cast<ushort2*>(kbf)[kidx] = o;
  float2 f; f.x = r0; f.y = r1;
#pragma unroll
  for (int rep = 0; rep < 4; ++rep) {
    int h = kvh * 4 + rep;
    reinterpret_cast<float2*>(keys)[((b * 16 + h) * 2048 + l) * 64 + i] = f;
  }
}

// ---------------- V pass: values output + transposed bf16 V ----------------
__global__ void v_proc_kernel(const float* __restrict__ xqkv, unsigned short* __restrict__ vt,
                              float* __restrict__ values) {
  int idx = blockIdx.x * 256 + threadIdx.x;   // element over (b,l,kv,d)
  int d = idx & 127;
  int kvh = (idx >> 7) & 3;
  int l = (idx >> 9) & 2047;
  int b = idx >> 20;
  float v = xqkv[(size_t)(b * 2048 + l) * 3072 + 2560 + kvh * 128 + d];
#pragma unroll
  for (int rep = 0; rep < 4; ++rep) {
    int h = kvh * 4 + rep;
    values[((size_t)(b * 16 + h) * 2048 + l) * 128 + d] = v;
  }
  vt[((size_t)(b * 4 + kvh) * 128 + d) * 2048 + l] = f32_to_bf16(v);
}

// ---------------- causal flash attention v5: barrier-free, LDS-free ----------------
// Each wave independently owns 32 q-rows, streams K/V from global (L2-resident,
// XCD-pinned). K fragment addressing bakes in the row permutation so the PV
// B-operand is a pure in-lane cvt_pk repack. No __syncthreads anywhere.
__global__ __launch_bounds__(256) void attn_kernel(
    const float* __restrict__ xq, const float* __restrict__ fc,
    const float* __restrict__ fs, const unsigned short* __restrict__ kbf,
    const unsigned short* __restrict__ vt, unsigned short* __restrict__ obf) {
  const int tid = threadIdx.x;
  const int w = tid >> 6, lane = tid & 63;
  const int lr = lane & 15, lg = lane >> 4;
  const int bid = blockIdx.x;
  const int g = bid & 7;                       // XCD pin: one (b,kv) per XCD
  const int slot = bid >> 3;                   // 0..63
  const int rep = slot & 3;
  const int cg = slot >> 2;                    // 0..15
  const int b = g >> 2, kv = g & 3;
  const int h = kv * 4 + rep;
  const int qc = 63 - (cg * 4 + w);            // q-chunk 0..63, longest first
  const float SCALE = 0.08838834764831845f;    // 1/sqrt(128)

  const int qr0 = qc * 32 + lr;                // t0 row
  const int qr1 = qr0 + 16;                    // t1 row

  // ---- fused RoPE Q-fragment build (B-operand layout) ----
  bf16x8 qf[2][4];
#pragma unroll
  for (int t = 0; t < 2; ++t) {
    const int qrow = t ? qr1 : qr0;
    const float* xqp = xq + (size_t)(b * 2048 + qrow) * 3072 + h * 128;
    const float* fcp = fc + qrow * 64;
    const float* fsp = fs + qrow * 64;
#pragma unroll
    for (int s = 0; s < 4; ++s) {
      float4 f0 = *reinterpret_cast<const float4*>(xqp + s * 32 + lg * 8);
      float4 f1 = *reinterpret_cast<const float4*>(xqp + s * 32 + lg * 8 + 4);
      float4 c4 = *reinterpret_cast<const float4*>(fcp + s * 16 + lg * 4);
      float4 s4 = *reinterpret_cast<const float4*>(fsp + s * 16 + lg * 4);
      union { bf16x8 v8; unsigned u[4]; } u;
      u.u[0] = pack2(f0.x * c4.x - f0.y * s4.x, f0.x * s4.x + f0.y * c4.x);
      u.u[1] = pack2(f0.z * c4.y - f0.w * s4.y, f0.z * s4.y + f0.w * c4.y);
      u.u[2] = pack2(f1.x * c4.z - f1.y * s4.z, f1.x * s4.z + f1.y * c4.z);
      u.u[3] = pack2(f1.z * c4.w - f1.w * s4.w, f1.z * s4.w + f1.w * c4.w);
      qf[t][s] = u.v8;
    }
  }

  f32x4 acc[2][8] = {};
  float mrow[2] = {-1e30f, -1e30f}, lsum[2] = {0.f, 0.f};

  const char* kgbase = (const char*)(kbf + (size_t)(b * 4 + kv) * 2048 * 128);
  const char* vgbase = (const char*)(vt + (size_t)(b * 4 + kv) * 128 * 2048);

  // permuted K row offset per c-tile: pi_inv(16c+lr) (loop-invariant, per-lane)
  int krp[4];
#pragma unroll
  for (int c = 0; c < 4; ++c)
    krp[c] = ((c >> 1) << 5) + (c & 1) + (((lr >> 2) & 3) << 3) + ((lr & 3) << 1);

  // per-t softmax + in-lane P repack
  auto softmax_t = [&](const f32x4* st, int t, bool mask, int qrow, int kb, bf16x8* pt) {
    float xv[4][4];
    float mt = -1e30f;
#pragma unroll
    for (int c = 0; c < 4; ++c)
#pragma unroll
      for (int r = 0; r < 4; ++r) {
        float v = st[c][r] * SCALE;
        if (mask) {
          int ka = kb + ((c >> 1) << 5) + (c & 1) + 8 * lg + 2 * r;
          v = (ka <= qrow) ? v : -1e30f;
        }
        xv[c][r] = v;
        mt = fmaxf(mt, v);
      }
    mt = fmaxf(mt, __shfl_xor(mt, 16));
    mt = fmaxf(mt, __shfl_xor(mt, 32));
    float facm = 1.0f;
    if (!__all(mt <= mrow[t] + 8.0f)) {        // defer-max (T13)
      float mnew = fmaxf(mrow[t], mt);
      facm = __expf(mrow[t] - mnew);
      mrow[t] = mnew;
#pragma unroll
      for (int dt = 0; dt < 8; ++dt)
#pragma unroll
        for (int r = 0; r < 4; ++r) acc[t][dt][r] *= facm;
    }
    float rs = 0.f;
    float pv[4][4];
#pragma unroll
    for (int c = 0; c < 4; ++c)
#pragma unroll
      for (int r = 0; r < 4; ++r) {
        float p = __expf(xv[c][r] - mrow[t]);
        pv[c][r] = p;
        rs += p;
      }
    rs += __shfl_xor(rs, 16);
    rs += __shfl_xor(rs, 32);
    lsum[t] = lsum[t] * facm + rs;
#pragma unroll
    for (int kk = 0; kk < 2; ++kk) {
      union { bf16x8 v8; unsigned u[4]; } u;
#pragma unroll
      for (int wd = 0; wd < 4; ++wd)
        u.u[wd] = pack2(pv[2 * kk][wd], pv[2 * kk + 1][wd]);
      pt[kk] = u.v8;
    }
  };

  const int nst = (qc >> 1) + 1;
  for (int j = 0; j < nst; ++j) {
    const int kb = j * 64;
    const bool msk = (j == nst - 1);
    // QK^T (swapped, permuted K rows straight from global/L2)
    f32x4 sT0[4], sT1[4];
    __builtin_amdgcn_s_setprio(1);
#pragma unroll
    for (int c = 0; c < 4; ++c) {
      bf16x8 kf[4];
#pragma unroll
      for (int s = 0; s < 4; ++s)
        kf[s] = *reinterpret_cast<const bf16x8*>(
            kgbase + (size_t)(kb + krp[c]) * 256 + s * 64 + lg * 16);
      f32x4 t0 = {0.f, 0.f, 0.f, 0.f}, t1 = {0.f, 0.f, 0.f, 0.f};
#pragma unroll
      for (int s = 0; s < 4; ++s) {
        t0 = __builtin_amdgcn_mfma_f32_16x16x32_bf16(kf[s], qf[0][s], t0, 0, 0, 0);
        t1 = __builtin_amdgcn_mfma_f32_16x16x32_bf16(kf[s], qf[1][s], t1, 0, 0, 0);
      }
      sT0[c] = t0; sT1[c] = t1;
    }
    __builtin_amdgcn_s_setprio(0);
    bf16x8 pt0[2], pt1[2];
    softmax_t(sT0, 0, msk, qr0, kb, pt0);
    softmax_t(sT1, 1, msk, qr1, kb, pt1);
    // PV: O^T += V^T * P^T (V rows straight from global/L2)
    __builtin_amdgcn_s_setprio(1);
#pragma unroll
    for (int dt = 0; dt < 8; ++dt) {
      const char* vrow = vgbase + (size_t)(dt * 16 + lr) * 4096 + (size_t)kb * 2 + lg * 16;
      bf16x8 v0 = *reinterpret_cast<const bf16x8*>(vrow);
      bf16x8 v1 = *reinterpret_cast<const bf16x8*>(vrow + 64);
      acc[0][dt] = __builtin_amdgcn_mfma_f32_16x16x32_bf16(v0, pt0[0], acc[0][dt], 0, 0, 0);
      acc[0][dt] = __builtin_amdgcn_mfma_f32_16x16x32_bf16(v1, pt0[1], acc[0][dt], 0, 0, 0);
      acc[1][dt] = __builtin_amdgcn_mfma_f32_16x16x32_bf16(v0, pt1[0], acc[1][dt], 0, 0, 0);
      acc[1][dt] = __builtin_amdgcn_mfma_f32_16x16x32_bf16(v1, pt1[1], acc[1][dt], 0, 0, 0);
    }
    __builtin_amdgcn_s_setprio(0);
  }

#pragma unroll
  for (int t = 0; t < 2; ++t) {
    const int qrow = t ? qr1 : qr0;
    float inv = 1.0f / lsum[t];
#pragma unroll
    for (int dt = 0; dt < 8; ++dt) {
      ushort4 o;
      o.x = f32_to_bf16(acc[t][dt][0] * inv);
      o.y = f32_to_bf16(acc[t][dt][1] * inv);
      o.z = f32_to_bf16(acc[t][dt][2] * inv);
      o.w = f32_to_bf16(acc[t][dt][3] * inv);
      *reinterpret_cast<ushort4*>(obf + ((size_t)(b * 2048 + qrow)) * 2048 + h * 128 + dt * 16 + lg * 4) = o;
    }
  }
}

// ---------------- host launch ----------------
extern "C" void kernel_launch(void* const* d_in, const int* in_sizes, int n_in,
                              void* d_out, int out_size, void* d_ws, size_t ws_size,
                              hipStream_t stream) {
  const float* x  = (const float*)d_in[0];
  const float* fc = (const float*)d_in[1];
  const float* fs = (const float*)d_in[2];
  const float* wq = (const float*)d_in[3];
  const float* wk = (const float*)d_in[4];
  const float* wv = (const float*)d_in[5];
  const float* wo = (const float*)d_in[6];

  float* out    = (float*)d_out;
  float* keys   = out + 8388608;
  float* values = out + 16777216;

  char* ws = (char*)d_ws;
  unsigned short* WQKV = (unsigned short*)(ws + 0);          // 12.6 MB: [wq;wk;wv] (3072 x 2048)
  unsigned short* WO   = (unsigned short*)(ws + 12582912);   // 8 MB
  unsigned short* XBF  = (unsigned short*)(ws + 20971520);   // 16 MB (reused as ATT)
  float*          XQKV = (float*)(ws + 37748736);            // 50.3 MB (4096 x 3072)
  unsigned short* KBF  = (unsigned short*)(ws + 88080384);   // 4 MB
  unsigned short* VTB  = (unsigned short*)(ws + 92274688);   // 4 MB
  unsigned short* ATT  = XBF;                                // alias: XBF dead after projection

  cast2_bf16_kernel<<<8192, 256, 0, stream>>>(wq, WQKV, 1048576, wo, WO);
  cast2_bf16_kernel<<<2048, 256, 0, stream>>>(wk, WQKV + 2048 * 2048, 262144,
                                              wv, WQKV + 2560 * 2048);
  cast_bf16_kernel<<<8192, 256, 0, stream>>>(x, XBF);

  // fused QKV projection: C (4096 x 3072) = XBF (4096 x 2048) * WQKV^T
  gemm_bt_kernel<<<dim3(24, 32), 256, 0, stream>>>(XBF, WQKV, XQKV, 4096, 3072, 2048);

  rope_k_kernel<<<4096, 256, 0, stream>>>(XQKV, fc, fs, KBF, keys);
  v_proc_kernel<<<8192, 256, 0, stream>>>(XQKV, VTB, values);

  attn_kernel<<<512, 256, 0, stream>>>(XQKV, fc, fs, KBF, VTB, ATT);

  gemm_bt_kernel<<<dim3(16, 32), 256, 0, stream>>>(ATT, WO, out, 4096, 2048, 2048);
}

// Round 6
// 297.420 us; speedup vs baseline: 1.2078x; 1.2078x over previous
//
#include <hip/hip_runtime.h>
#include <hip/hip_bf16.h>

using bf16x8 = __attribute__((ext_vector_type(8))) short;
using f32x4  = __attribute__((ext_vector_type(4))) float;

__device__ __forceinline__ unsigned short f32_to_bf16(float f) {
  unsigned u = __float_as_uint(f);
  u += 0x7FFFu + ((u >> 16) & 1u);   // RNE
  return (unsigned short)(u >> 16);
}
__device__ __forceinline__ unsigned pack2(float lo, float hi) {
  __hip_bfloat162 h = __float22bfloat162_rn(make_float2(lo, hi)); // v_cvt_pk path
  return *reinterpret_cast<unsigned*>(&h);
}
__device__ __forceinline__ void gload_lds16(const void* g, void* l) {
  __builtin_amdgcn_global_load_lds(
      (const __attribute__((address_space(1))) unsigned int*)g,
      (__attribute__((address_space(3))) unsigned int*)l, 16, 0, 0);
}

// ---------------- elementwise casts ----------------
__global__ void cast_bf16_kernel(const float* __restrict__ src,
                                 unsigned short* __restrict__ dst) {
  int i = blockIdx.x * blockDim.x + threadIdx.x;
  float4 v = reinterpret_cast<const float4*>(src)[i];
  ushort4 o;
  o.x = f32_to_bf16(v.x); o.y = f32_to_bf16(v.y);
  o.z = f32_to_bf16(v.z); o.w = f32_to_bf16(v.w);
  reinterpret_cast<ushort4*>(dst)[i] = o;
}
__global__ void cast2_bf16_kernel(const float* __restrict__ s0, unsigned short* __restrict__ d0,
                                  int n0v, const float* __restrict__ s1,
                                  unsigned short* __restrict__ d1) {
  int i = blockIdx.x * blockDim.x + threadIdx.x;
  const float* s; unsigned short* d; int j;
  if (i < n0v) { s = s0; d = d0; j = i; } else { s = s1; d = d1; j = i - n0v; }
  float4 v = reinterpret_cast<const float4*>(s)[j];
  ushort4 o;
  o.x = f32_to_bf16(v.x); o.y = f32_to_bf16(v.y);
  o.z = f32_to_bf16(v.z); o.w = f32_to_bf16(v.w);
  reinterpret_cast<ushort4*>(d)[j] = o;
}

// ---------------- GEMM: C[M,N] = A[M,K] * W[N,K]^T  (m97 structure) ----------------
__global__ __launch_bounds__(256) void gemm_bt_kernel(
    const unsigned short* __restrict__ A, const unsigned short* __restrict__ Bw,
    float* __restrict__ C, int M, int N, int K) {
  __shared__ unsigned short As[128 * 32];
  __shared__ unsigned short Bs[128 * 32];
  const int tid = threadIdx.x;
  const int bn = blockIdx.x, bm = blockIdx.y;
  const int w = tid >> 6, lane = tid & 63;
  const int wr = w >> 1, wc = w & 1;
  const int lr = lane & 15, lg = lane >> 4;
  const int srow = lane >> 2;
  const int scolb = (lane & 3) * 16;
  f32x4 acc[4][4] = {};
  for (int k0 = 0; k0 < K; k0 += 32) {
    __syncthreads();
#pragma unroll
    for (int i = 0; i < 2; ++i) {
      int row = w * 32 + i * 16 + srow;
      gload_lds16((const char*)A + ((size_t)(bm * 128 + row) * K + k0) * 2 + scolb,
                  (char*)As + w * 2048 + i * 1024);
      gload_lds16((const char*)Bw + ((size_t)(bn * 128 + row) * K + k0) * 2 + scolb,
                  (char*)Bs + w * 2048 + i * 1024);
    }
    __syncthreads();
    bf16x8 af[4], bfr[4];
#pragma unroll
    for (int i = 0; i < 4; ++i)
      af[i] = *reinterpret_cast<const bf16x8*>((char*)As + (wr * 64 + i * 16 + lr) * 64 + lg * 16);
#pragma unroll
    for (int j = 0; j < 4; ++j)
      bfr[j] = *reinterpret_cast<const bf16x8*>((char*)Bs + (wc * 64 + j * 16 + lr) * 64 + lg * 16);
#pragma unroll
    for (int i = 0; i < 4; ++i)
#pragma unroll
      for (int j = 0; j < 4; ++j)
        acc[i][j] = __builtin_amdgcn_mfma_f32_16x16x32_bf16(af[i], bfr[j], acc[i][j], 0, 0, 0);
  }
#pragma unroll
  for (int i = 0; i < 4; ++i) {
    const int m = bm * 128 + wr * 64 + i * 16 + lg * 4;
#pragma unroll
    for (int j = 0; j < 4; ++j) {
      const int n = bn * 128 + wc * 64 + j * 16 + lr;
#pragma unroll
      for (int r = 0; r < 4; ++r)
        C[(size_t)(m + r) * N + n] = acc[i][j][r];
    }
  }
}

// ---------------- RoPE on K + keys output (reads fused XQKV, ld=3072) ----------------
__global__ void rope_k_kernel(const float* __restrict__ xqkv, const float* __restrict__ fc,
                              const float* __restrict__ fs, unsigned short* __restrict__ kbf,
                              float* __restrict__ keys) {
  int idx = blockIdx.x * 256 + threadIdx.x;   // pair index over (b,l,kv,i)
  int i = idx & 63;
  int kvh = (idx >> 6) & 3;
  int l = (idx >> 8) & 2047;
  int b = idx >> 19;
  float2 t = reinterpret_cast<const float2*>(xqkv)[(size_t)(b * 2048 + l) * 1536 + 1024 + kvh * 64 + i];
  float c = fc[l * 64 + i], s = fs[l * 64 + i];
  float r0 = t.x * c - t.y * s;
  float r1 = t.x * s + t.y * c;
  int kidx = ((b * 4 + kvh) * 2048 + l) * 64 + i;
  ushort2 o; o.x = f32_to_bf16(r0); o.y = f32_to_bf16(r1);
  reinterpret_cast<ushort2*>(kbf)[kidx] = o;
  float2 f; f.x = r0; f.y = r1;
#pragma unroll
  for (int rep = 0; rep < 4; ++rep) {
    int h = kvh * 4 + rep;
    reinterpret_cast<float2*>(keys)[((b * 16 + h) * 2048 + l) * 64 + i] = f;
  }
}

// ---------------- V pass: values output + transposed bf16 V ----------------
__global__ void v_proc_kernel(const float* __restrict__ xqkv, unsigned short* __restrict__ vt,
                              float* __restrict__ values) {
  int idx = blockIdx.x * 256 + threadIdx.x;   // element over (b,l,kv,d)
  int d = idx & 127;
  int kvh = (idx >> 7) & 3;
  int l = (idx >> 9) & 2047;
  int b = idx >> 20;
  float v = xqkv[(size_t)(b * 2048 + l) * 3072 + 2560 + kvh * 128 + d];
#pragma unroll
  for (int rep = 0; rep < 4; ++rep) {
    int h = kvh * 4 + rep;
    values[((size_t)(b * 16 + h) * 2048 + l) * 128 + d] = v;
  }
  vt[((size_t)(b * 4 + kvh) * 128 + d) * 2048 + l] = f32_to_bf16(v);
}

// ---------------- causal flash attention v6: counted-vmcnt double-buffer ----------------
// Pipeline per step: stage(j+1) -> s_waitcnt vmcnt(8) -> s_barrier -> compute(j)
// -> s_barrier. Next tile's 8 loads stay in flight across the whole compute phase.
// Q pre-scaled by SCALE*log2e (Q is internal-only), softmax in exp2 domain.
__global__ __launch_bounds__(256) void attn_kernel(
    const float* __restrict__ xq, const float* __restrict__ fc,
    const float* __restrict__ fs, const unsigned short* __restrict__ kbf,
    const unsigned short* __restrict__ vt, unsigned short* __restrict__ obf) {
  __shared__ unsigned short Ks[2][64 * 128];   // [buf][slot][d], XOR-swizzled, row-permuted
  __shared__ unsigned short Vs[2][128 * 64];   // [buf][d][k], XOR-swizzled
  const int tid = threadIdx.x;
  const int w = tid >> 6, lane = tid & 63;
  const int lr = lane & 15, lg = lane >> 4;
  const int bid = blockIdx.x;
  const int g = bid & 7;                       // XCD pin: one (b,kv) pair per XCD
  const int slot = bid >> 3;
  const int u = slot >> 2;                     // 0..15
  const int qt = (u < 8) ? (15 - u) : (u - 8); // bid & bid+256 sum to 36 steps/CU
  const int rep = slot & 3;
  const int b = g >> 2, kv = g & 3;
  const int h = kv * 4 + rep;
  const float ALPHA = 0.12751791437664778f;    // (1/sqrt(128)) * log2(e)
  const int swz = (lr & 7) << 4;

  const int qr0 = qt * 128 + w * 16 + lr;
  const int qr1 = qr0 + 64;

  // ---- fused RoPE Q-fragment build, pre-scaled by ALPHA ----
  bf16x8 qf[2][4];
#pragma unroll
  for (int t = 0; t < 2; ++t) {
    const int qrow = t ? qr1 : qr0;
    const float* xqp = xq + (size_t)(b * 2048 + qrow) * 3072 + h * 128;
    const float* fcp = fc + qrow * 64;
    const float* fsp = fs + qrow * 64;
#pragma unroll
    for (int s = 0; s < 4; ++s) {
      float4 f0 = *reinterpret_cast<const float4*>(xqp + s * 32 + lg * 8);
      float4 f1 = *reinterpret_cast<const float4*>(xqp + s * 32 + lg * 8 + 4);
      float4 c4 = *reinterpret_cast<const float4*>(fcp + s * 16 + lg * 4);
      float4 s4 = *reinterpret_cast<const float4*>(fsp + s * 16 + lg * 4);
      c4.x *= ALPHA; c4.y *= ALPHA; c4.z *= ALPHA; c4.w *= ALPHA;
      s4.x *= ALPHA; s4.y *= ALPHA; s4.z *= ALPHA; s4.w *= ALPHA;
      union { bf16x8 v8; unsigned u[4]; } uu;
      uu.u[0] = pack2(f0.x * c4.x - f0.y * s4.x, f0.x * s4.x + f0.y * c4.x);
      uu.u[1] = pack2(f0.z * c4.y - f0.w * s4.y, f0.z * s4.y + f0.w * c4.y);
      uu.u[2] = pack2(f1.x * c4.z - f1.y * s4.z, f1.x * s4.z + f1.y * c4.z);
      uu.u[3] = pack2(f1.z * c4.w - f1.w * s4.w, f1.z * s4.w + f1.w * c4.w);
      qf[t][s] = uu.v8;
    }
  }

  f32x4 acc[2][8] = {};
  float mrow[2] = {-1e30f, -1e30f}, lsum[2] = {0.f, 0.f};

  const char* kgbase = (const char*)(kbf + (size_t)(b * 4 + kv) * 2048 * 128);
  const char* vgbase = (const char*)(vt + (size_t)(b * 4 + kv) * 128 * 2048);

  // staging source offsets (loop-invariant); K global row permuted by pi
  int ksrc[4], vsrc[4];
#pragma unroll
  for (int i = 0; i < 4; ++i) {
    int p = w * 4096 + i * 1024 + lane * 16;
    int krow = p >> 8;
    int kperm = ((krow >> 5) << 5) + ((krow >> 4) & 1) + (((krow >> 2) & 3) << 3) + ((krow & 3) << 1);
    int kcol = (p & 255) ^ ((krow & 7) << 4);
    ksrc[i] = kperm * 256 + kcol;
    int drow = p >> 7;
    int dcol = (p & 127) ^ ((drow & 7) << 4);
    vsrc[i] = drow * 4096 + dcol;
  }

  auto stage = [&](int j, int buf) {
    const int kb = j * 64;
    const char* kg = kgbase + (size_t)kb * 256;
    const char* vg = vgbase + (size_t)kb * 2;
#pragma unroll
    for (int i = 0; i < 4; ++i) {
      gload_lds16(kg + ksrc[i], (char*)Ks[buf] + w * 4096 + i * 1024);
      gload_lds16(vg + vsrc[i], (char*)Vs[buf] + w * 4096 + i * 1024);
    }
  };

  // per-t softmax (exp2 domain, S pre-scaled) + in-lane P repack
  auto softmax_t = [&](const f32x4* st, int t, bool mask, int qrow, int kb, bf16x8* pt) {
    float xv[4][4];
    float mt = -1e30f;
#pragma unroll
    for (int c = 0; c < 4; ++c)
#pragma unroll
      for (int r = 0; r < 4; ++r) {
        float v = st[c][r];
        if (mask) {
          int ka = kb + ((c >> 1) << 5) + (c & 1) + 8 * lg + 2 * r;
          v = (ka <= qrow) ? v : -1e30f;
        }
        xv[c][r] = v;
        mt = fmaxf(mt, v);
      }
    mt = fmaxf(mt, __shfl_xor(mt, 16));
    mt = fmaxf(mt, __shfl_xor(mt, 32));
    float facm = 1.0f;
    if (!__all(mt <= mrow[t] + 8.0f)) {        // defer-max (T13), log2 units
      float mnew = fmaxf(mrow[t], mt);
      facm = exp2f(mrow[t] - mnew);
      mrow[t] = mnew;
#pragma unroll
      for (int dt = 0; dt < 8; ++dt)
#pragma unroll
        for (int r = 0; r < 4; ++r) acc[t][dt][r] *= facm;
    }
    float rs = 0.f;
    float pv[4][4];
#pragma unroll
    for (int c = 0; c < 4; ++c)
#pragma unroll
      for (int r = 0; r < 4; ++r) {
        float p = exp2f(xv[c][r] - mrow[t]);
        pv[c][r] = p;
        rs += p;
      }
    rs += __shfl_xor(rs, 16);
    rs += __shfl_xor(rs, 32);
    lsum[t] = lsum[t] * facm + rs;
#pragma unroll
    for (int kk = 0; kk < 2; ++kk) {
      union { bf16x8 v8; unsigned u[4]; } uu;
#pragma unroll
      for (int wd = 0; wd < 4; ++wd)
        uu.u[wd] = pack2(pv[2 * kk][wd], pv[2 * kk + 1][wd]);
      pt[kk] = uu.v8;
    }
  };

  const int nst = 2 * qt + 2;
  stage(0, 0);
  int cur = 0;
  for (int j = 0; j < nst; ++j) {
    if (j + 1 < nst) {
      stage(j + 1, cur ^ 1);
      asm volatile("s_waitcnt vmcnt(8)" ::: "memory");   // tile j resident; j+1 in flight
    } else {
      asm volatile("s_waitcnt vmcnt(0)" ::: "memory");
    }
    __builtin_amdgcn_s_barrier();
    __builtin_amdgcn_sched_barrier(0);
    const int kb = j * 64;
    const bool only1 = (j == nst - 1);
    const bool do0 = !only1;
    const bool m0 = (j == nst - 2);
    const bool m1 = only1;
    // QK^T (swapped): S^T rows = permuted keys, cols = q
    f32x4 sT0[4], sT1[4];
    __builtin_amdgcn_s_setprio(1);
#pragma unroll
    for (int c = 0; c < 4; ++c) {
      bf16x8 kf[4];
#pragma unroll
      for (int s = 0; s < 4; ++s)
        kf[s] = *reinterpret_cast<const bf16x8*>((char*)Ks[cur] + (((c * 16 + lr) * 256 + s * 64 + lg * 16) ^ swz));
      f32x4 t0 = {0.f, 0.f, 0.f, 0.f}, t1 = {0.f, 0.f, 0.f, 0.f};
#pragma unroll
      for (int s = 0; s < 4; ++s) {
        if (do0) t0 = __builtin_amdgcn_mfma_f32_16x16x32_bf16(kf[s], qf[0][s], t0, 0, 0, 0);
        t1 = __builtin_amdgcn_mfma_f32_16x16x32_bf16(kf[s], qf[1][s], t1, 0, 0, 0);
      }
      sT0[c] = t0; sT1[c] = t1;
    }
    __builtin_amdgcn_s_setprio(0);
    bf16x8 pt0[2], pt1[2];
    if (do0) softmax_t(sT0, 0, m0, qr0, kb, pt0);
    softmax_t(sT1, 1, m1, qr1, kb, pt1);
    // PV: O^T += V^T * P^T
    __builtin_amdgcn_s_setprio(1);
#pragma unroll
    for (int dt = 0; dt < 8; ++dt) {
      bf16x8 v0 = *reinterpret_cast<const bf16x8*>((char*)Vs[cur] + (((dt * 16 + lr) * 128 + lg * 16) ^ swz));
      bf16x8 v1 = *reinterpret_cast<const bf16x8*>((char*)Vs[cur] + (((dt * 16 + lr) * 128 + 64 + lg * 16) ^ swz));
      if (do0) {
        acc[0][dt] = __builtin_amdgcn_mfma_f32_16x16x32_bf16(v0, pt0[0], acc[0][dt], 0, 0, 0);
        acc[0][dt] = __builtin_amdgcn_mfma_f32_16x16x32_bf16(v1, pt0[1], acc[0][dt], 0, 0, 0);
      }
      acc[1][dt] = __builtin_amdgcn_mfma_f32_16x16x32_bf16(v0, pt1[0], acc[1][dt], 0, 0, 0);
      acc[1][dt] = __builtin_amdgcn_mfma_f32_16x16x32_bf16(v1, pt1[1], acc[1][dt], 0, 0, 0);
    }
    __builtin_amdgcn_s_setprio(0);
    __builtin_amdgcn_sched_barrier(0);
    __builtin_amdgcn_s_barrier();    // all waves done reading buf[cur] before overwrite
    cur ^= 1;
  }

#pragma unroll
  for (int t = 0; t < 2; ++t) {
    const int qrow = t ? qr1 : qr0;
    float inv = 1.0f / lsum[t];
#pragma unroll
    for (int dt = 0; dt < 8; ++dt) {
      ushort4 o;
      o.x = f32_to_bf16(acc[t][dt][0] * inv);
      o.y = f32_to_bf16(acc[t][dt][1] * inv);
      o.z = f32_to_bf16(acc[t][dt][2] * inv);
      o.w = f32_to_bf16(acc[t][dt][3] * inv);
      *reinterpret_cast<ushort4*>(obf + ((size_t)(b * 2048 + qrow)) * 2048 + h * 128 + dt * 16 + lg * 4) = o;
    }
  }
}

// ---------------- host launch ----------------
extern "C" void kernel_launch(void* const* d_in, const int* in_sizes, int n_in,
                              void* d_out, int out_size, void* d_ws, size_t ws_size,
                              hipStream_t stream) {
  const float* x  = (const float*)d_in[0];
  const float* fc = (const float*)d_in[1];
  const float* fs = (const float*)d_in[2];
  const float* wq = (const float*)d_in[3];
  const float* wk = (const float*)d_in[4];
  const float* wv = (const float*)d_in[5];
  const float* wo = (const float*)d_in[6];

  float* out    = (float*)d_out;
  float* keys   = out + 8388608;
  float* values = out + 16777216;

  char* ws = (char*)d_ws;
  unsigned short* WQKV = (unsigned short*)(ws + 0);          // 12.6 MB: [wq;wk;wv] (3072 x 2048)
  unsigned short* WO   = (unsigned short*)(ws + 12582912);   // 8 MB
  unsigned short* XBF  = (unsigned short*)(ws + 20971520);   // 16 MB (reused as ATT)
  float*          XQKV = (float*)(ws + 37748736);            // 50.3 MB (4096 x 3072)
  unsigned short* KBF  = (unsigned short*)(ws + 88080384);   // 4 MB
  unsigned short* VTB  = (unsigned short*)(ws + 92274688);   // 4 MB
  unsigned short* ATT  = XBF;                                // alias: XBF dead after projection

  cast2_bf16_kernel<<<8192, 256, 0, stream>>>(wq, WQKV, 1048576, wo, WO);
  cast2_bf16_kernel<<<2048, 256, 0, stream>>>(wk, WQKV + 2048 * 2048, 262144,
                                              wv, WQKV + 2560 * 2048);
  cast_bf16_kernel<<<8192, 256, 0, stream>>>(x, XBF);

  // fused QKV projection: C (4096 x 3072) = XBF (4096 x 2048) * WQKV^T
  gemm_bt_kernel<<<dim3(24, 32), 256, 0, stream>>>(XBF, WQKV, XQKV, 4096, 3072, 2048);

  rope_k_kernel<<<4096, 256, 0, stream>>>(XQKV, fc, fs, KBF, keys);
  v_proc_kernel<<<8192, 256, 0, stream>>>(XQKV, VTB, values);

  attn_kernel<<<512, 256, 0, stream>>>(XQKV, fc, fs, KBF, VTB, ATT);

  gemm_bt_kernel<<<dim3(16, 32), 256, 0, stream>>>(ATT, WO, out, 4096, 2048, 2048);
}

// Round 7
// 261.950 us; speedup vs baseline: 1.3714x; 1.1354x over previous
//
#include <hip/hip_runtime.h>
#include <hip/hip_bf16.h>

using bf16x8 = __attribute__((ext_vector_type(8))) short;
using f32x4  = __attribute__((ext_vector_type(4))) float;

__device__ __forceinline__ unsigned short f32_to_bf16(float f) {
  unsigned u = __float_as_uint(f);
  u += 0x7FFFu + ((u >> 16) & 1u);   // RNE
  return (unsigned short)(u >> 16);
}
__device__ __forceinline__ unsigned pack2(float lo, float hi) {
  __hip_bfloat162 h = __float22bfloat162_rn(make_float2(lo, hi)); // v_cvt_pk path
  return *reinterpret_cast<unsigned*>(&h);
}
__device__ __forceinline__ void gload_lds16(const void* g, void* l) {
  __builtin_amdgcn_global_load_lds(
      (const __attribute__((address_space(1))) unsigned int*)g,
      (__attribute__((address_space(3))) unsigned int*)l, 16, 0, 0);
}

// ---------------- elementwise casts ----------------
__global__ void cast_bf16_kernel(const float* __restrict__ src,
                                 unsigned short* __restrict__ dst) {
  int i = blockIdx.x * blockDim.x + threadIdx.x;
  float4 v = reinterpret_cast<const float4*>(src)[i];
  ushort4 o;
  o.x = f32_to_bf16(v.x); o.y = f32_to_bf16(v.y);
  o.z = f32_to_bf16(v.z); o.w = f32_to_bf16(v.w);
  reinterpret_cast<ushort4*>(dst)[i] = o;
}
__global__ void cast2_bf16_kernel(const float* __restrict__ s0, unsigned short* __restrict__ d0,
                                  int n0v, const float* __restrict__ s1,
                                  unsigned short* __restrict__ d1) {
  int i = blockIdx.x * blockDim.x + threadIdx.x;
  const float* s; unsigned short* d; int j;
  if (i < n0v) { s = s0; d = d0; j = i; } else { s = s1; d = d1; j = i - n0v; }
  float4 v = reinterpret_cast<const float4*>(s)[j];
  ushort4 o;
  o.x = f32_to_bf16(v.x); o.y = f32_to_bf16(v.y);
  o.z = f32_to_bf16(v.z); o.w = f32_to_bf16(v.w);
  reinterpret_cast<ushort4*>(d)[j] = o;
}

// ---------------- GEMM v2: C[M,N] = A[M,K] * W[N,K]^T ----------------
// BM x 256 tile, BK=64, 8 waves (2 x 4), double-buffered LDS, per-row XOR swizzle,
// counted vmcnt (never 0 in loop), per-quadrant ds_read/MFMA interleave + setprio.
template <int BM>
__global__ __launch_bounds__(512, 2) void gemm256_kernel(
    const unsigned short* __restrict__ A, const unsigned short* __restrict__ Bw,
    float* __restrict__ C, int M, int N, int K) {
  constexpr int ABYTES = BM * 128;          // BM rows x 64 bf16
  constexpr int BBYTES = 256 * 128;         // 256 rows x 64 bf16
  constexpr int BUFB   = ABYTES + BBYTES;
  constexpr int ALOADS = BM / 64;           // 16B loads per thread per K-step (A)
  constexpr int WROWS  = BM / 32;           // 16-row frags per wave
  __shared__ __align__(16) char Lsh[2 * BUFB];

  const int tid = threadIdx.x;
  const int wid = tid >> 6, lane = tid & 63;
  const int lr = lane & 15, lg = lane >> 4;
  const int wr = wid >> 2, wc = wid & 3;    // 2 x 4 wave grid
  const int bn = blockIdx.x, bm = blockIdx.y;
  const int x0 = lg * 16;

  f32x4 acc[WROWS][4] = {};

  const char* Ag = (const char*)A + (size_t)(bm * BM) * K * 2;
  const char* Bg = (const char*)Bw + (size_t)(bn * 256) * K * 2;

  // staging source offsets (per-lane, swizzled); dest is linear (rule 21)
  int aoff[ALOADS], boff[4];
#pragma unroll
  for (int i = 0; i < ALOADS; ++i) {
    int lin = wid * (BM * 16) + i * 1024 + lane * 16;
    int grow = lin >> 7;
    int gcol = (lin & 127) ^ ((grow & 7) << 4);
    aoff[i] = grow * (K * 2) + gcol;
  }
#pragma unroll
  for (int i = 0; i < 4; ++i) {
    int lin = wid * 4096 + i * 1024 + lane * 16;
    int grow = lin >> 7;
    int gcol = (lin & 127) ^ ((grow & 7) << 4);
    boff[i] = grow * (K * 2) + gcol;
  }

  auto stage = [&](int s, int buf) {
    const int kb = s * 128;                 // byte offset along K
    char* Lb = Lsh + buf * BUFB;
#pragma unroll
    for (int i = 0; i < ALOADS; ++i)
      gload_lds16(Ag + aoff[i] + kb, Lb + wid * (BM * 16) + i * 1024);
#pragma unroll
    for (int i = 0; i < 4; ++i)
      gload_lds16(Bg + boff[i] + kb, Lb + ABYTES + wid * 4096 + i * 1024);
  };

  auto kstep = [&](char* Lb) {
    bf16x8 bfr[4][2];
#pragma unroll
    for (int fc = 0; fc < 4; ++fc) {
      const int row = wc * 64 + fc * 16 + lr;
      const int base = ABYTES + row * 128;
      const int sw = (row & 7) << 4;
#pragma unroll
      for (int ks = 0; ks < 2; ++ks)
        bfr[fc][ks] = *reinterpret_cast<const bf16x8*>(Lb + base + ((ks * 64 + x0) ^ sw));
    }
#pragma unroll
    for (int q = 0; q < WROWS / 2; ++q) {
      bf16x8 af[2][2];
#pragma unroll
      for (int t = 0; t < 2; ++t) {
        const int row = wr * (BM / 2) + (2 * q + t) * 16 + lr;
        const int base = row * 128;
        const int sw = (row & 7) << 4;
#pragma unroll
        for (int ks = 0; ks < 2; ++ks)
          af[t][ks] = *reinterpret_cast<const bf16x8*>(Lb + base + ((ks * 64 + x0) ^ sw));
      }
      asm volatile("s_waitcnt lgkmcnt(0)" ::: "memory");
      __builtin_amdgcn_sched_barrier(0);
      __builtin_amdgcn_s_setprio(1);
#pragma unroll
      for (int t = 0; t < 2; ++t)
#pragma unroll
        for (int fc = 0; fc < 4; ++fc) {
          acc[2 * q + t][fc] = __builtin_amdgcn_mfma_f32_16x16x32_bf16(af[t][0], bfr[fc][0], acc[2 * q + t][fc], 0, 0, 0);
          acc[2 * q + t][fc] = __builtin_amdgcn_mfma_f32_16x16x32_bf16(af[t][1], bfr[fc][1], acc[2 * q + t][fc], 0, 0, 0);
        }
      __builtin_amdgcn_s_setprio(0);
    }
  };

  const int NST = K >> 6;                   // 32
  stage(0, 0);
  for (int it = 0; it < NST / 2; ++it) {
    // ---- step 2it (buf 0) ----
    __builtin_amdgcn_s_barrier();           // B1: buf1 free (prev reads complete)
    stage(2 * it + 1, 1);
    if constexpr (BM == 256) asm volatile("s_waitcnt vmcnt(8)" ::: "memory");
    else                     asm volatile("s_waitcnt vmcnt(6)" ::: "memory");
    __builtin_amdgcn_s_barrier();           // B2: buf0 resident for all waves
    kstep(Lsh);
    // ---- step 2it+1 (buf 1) ----
    __builtin_amdgcn_s_barrier();           // B1: buf0 free
    if (it < NST / 2 - 1) {
      stage(2 * it + 2, 0);
      if constexpr (BM == 256) asm volatile("s_waitcnt vmcnt(8)" ::: "memory");
      else                     asm volatile("s_waitcnt vmcnt(6)" ::: "memory");
    } else {
      asm volatile("s_waitcnt vmcnt(0)" ::: "memory");
    }
    __builtin_amdgcn_s_barrier();           // B2: buf1 resident
    kstep(Lsh + BUFB);
  }

#pragma unroll
  for (int fr = 0; fr < WROWS; ++fr) {
    const int m = bm * BM + wr * (BM / 2) + fr * 16 + lg * 4;
#pragma unroll
    for (int fc = 0; fc < 4; ++fc) {
      const int n = bn * 256 + wc * 64 + fc * 16 + lr;
#pragma unroll
      for (int r = 0; r < 4; ++r)
        C[(size_t)(m + r) * N + n] = acc[fr][fc][r];
    }
  }
}

// ---------------- RoPE on K + keys output (reads fused XQKV, ld=3072) ----------------
__global__ void rope_k_kernel(const float* __restrict__ xqkv, const float* __restrict__ fc,
                              const float* __restrict__ fs, unsigned short* __restrict__ kbf,
                              float* __restrict__ keys) {
  int idx = blockIdx.x * 256 + threadIdx.x;   // pair index over (b,l,kv,i)
  int i = idx & 63;
  int kvh = (idx >> 6) & 3;
  int l = (idx >> 8) & 2047;
  int b = idx >> 19;
  float2 t = reinterpret_cast<const float2*>(xqkv)[(size_t)(b * 2048 + l) * 1536 + 1024 + kvh * 64 + i];
  float c = fc[l * 64 + i], s = fs[l * 64 + i];
  float r0 = t.x * c - t.y * s;
  float r1 = t.x * s + t.y * c;
  int kidx = ((b * 4 + kvh) * 2048 + l) * 64 + i;
  ushort2 o; o.x = f32_to_bf16(r0); o.y = f32_to_bf16(r1);
  reinterpret_cast<ushort2*>(kbf)[kidx] = o;
  float2 f; f.x = r0; f.y = r1;
#pragma unroll
  for (int rep = 0; rep < 4; ++rep) {
    int h = kvh * 4 + rep;
    reinterpret_cast<float2*>(keys)[((b * 16 + h) * 2048 + l) * 64 + i] = f;
  }
}

// ---------------- V pass: values output + transposed bf16 V ----------------
__global__ void v_proc_kernel(const float* __restrict__ xqkv, unsigned short* __restrict__ vt,
                              float* __restrict__ values) {
  int idx = blockIdx.x * 256 + threadIdx.x;   // element over (b,l,kv,d)
  int d = idx & 127;
  int kvh = (idx >> 7) & 3;
  int l = (idx >> 9) & 2047;
  int b = idx >> 20;
  float v = xqkv[(size_t)(b * 2048 + l) * 3072 + 2560 + kvh * 128 + d];
#pragma unroll
  for (int rep = 0; rep < 4; ++rep) {
    int h = kvh * 4 + rep;
    values[((size_t)(b * 16 + h) * 2048 + l) * 128 + d] = v;
  }
  vt[((size_t)(b * 4 + kvh) * 128 + d) * 2048 + l] = f32_to_bf16(v);
}

// ---------------- causal flash attention v7: single-buffer (best measured) ----------------
// Single 32KB K/V staging (3 blocks/CU), 2 syncthreads per step, balanced pairing,
// exp2-domain softmax, K-row-permuted LDS -> in-lane cvt_pk P repack, XCD pin.
__global__ __launch_bounds__(256) void attn_kernel(
    const float* __restrict__ xq, const float* __restrict__ fc,
    const float* __restrict__ fs, const unsigned short* __restrict__ kbf,
    const unsigned short* __restrict__ vt, unsigned short* __restrict__ obf) {
  __shared__ unsigned short Ks[64 * 128];      // [slot][d], XOR-swizzled, row-permuted
  __shared__ unsigned short Vs[128 * 64];      // [d][k],  XOR-swizzled
  const int tid = threadIdx.x;
  const int w = tid >> 6, lane = tid & 63;
  const int lr = lane & 15, lg = lane >> 4;
  const int bid = blockIdx.x;
  const int g = bid & 7;                       // XCD pin: one (b,kv) pair per XCD
  const int slot = bid >> 3;
  const int u = slot >> 2;                     // 0..15
  const int qt = (u < 8) ? (15 - u) : (u - 8); // bid & bid+256 sum to 36 steps
  const int rep = slot & 3;
  const int b = g >> 2, kv = g & 3;
  const int h = kv * 4 + rep;
  const float ALPHA = 0.12751791437664778f;    // (1/sqrt(128)) * log2(e)
  const int swz = (lr & 7) << 4;

  const int qr0 = qt * 128 + w * 16 + lr;
  const int qr1 = qr0 + 64;

  // ---- fused RoPE Q-fragment build, pre-scaled by ALPHA ----
  bf16x8 qf[2][4];
#pragma unroll
  for (int t = 0; t < 2; ++t) {
    const int qrow = t ? qr1 : qr0;
    const float* xqp = xq + (size_t)(b * 2048 + qrow) * 3072 + h * 128;
    const float* fcp = fc + qrow * 64;
    const float* fsp = fs + qrow * 64;
#pragma unroll
    for (int s = 0; s < 4; ++s) {
      float4 f0 = *reinterpret_cast<const float4*>(xqp + s * 32 + lg * 8);
      float4 f1 = *reinterpret_cast<const float4*>(xqp + s * 32 + lg * 8 + 4);
      float4 c4 = *reinterpret_cast<const float4*>(fcp + s * 16 + lg * 4);
      float4 s4 = *reinterpret_cast<const float4*>(fsp + s * 16 + lg * 4);
      c4.x *= ALPHA; c4.y *= ALPHA; c4.z *= ALPHA; c4.w *= ALPHA;
      s4.x *= ALPHA; s4.y *= ALPHA; s4.z *= ALPHA; s4.w *= ALPHA;
      union { bf16x8 v8; unsigned u[4]; } uu;
      uu.u[0] = pack2(f0.x * c4.x - f0.y * s4.x, f0.x * s4.x + f0.y * c4.x);
      uu.u[1] = pack2(f0.z * c4.y - f0.w * s4.y, f0.z * s4.y + f0.w * c4.y);
      uu.u[2] = pack2(f1.x * c4.z - f1.y * s4.z, f1.x * s4.z + f1.y * c4.z);
      uu.u[3] = pack2(f1.z * c4.w - f1.w * s4.w, f1.z * s4.w + f1.w * c4.w);
      qf[t][s] = uu.v8;
    }
  }

  f32x4 acc[2][8] = {};
  float mrow[2] = {-1e30f, -1e30f}, lsum[2] = {0.f, 0.f};

  const char* kgbase = (const char*)(kbf + (size_t)(b * 4 + kv) * 2048 * 128);
  const char* vgbase = (const char*)(vt + (size_t)(b * 4 + kv) * 128 * 2048);

  int ksrc[4], vsrc[4];
#pragma unroll
  for (int i = 0; i < 4; ++i) {
    int p = w * 4096 + i * 1024 + lane * 16;
    int krow = p >> 8;
    int kperm = ((krow >> 5) << 5) + ((krow >> 4) & 1) + (((krow >> 2) & 3) << 3) + ((krow & 3) << 1);
    int kcol = (p & 255) ^ ((krow & 7) << 4);
    ksrc[i] = kperm * 256 + kcol;
    int drow = p >> 7;
    int dcol = (p & 127) ^ ((drow & 7) << 4);
    vsrc[i] = drow * 4096 + dcol;
  }

  // per-t softmax (exp2 domain) + in-lane P repack
  auto softmax_t = [&](const f32x4* st, int t, bool mask, int qrow, int kb, bf16x8* pt) {
    float xv[4][4];
    float mt = -1e30f;
#pragma unroll
    for (int c = 0; c < 4; ++c)
#pragma unroll
      for (int r = 0; r < 4; ++r) {
        float v = st[c][r];
        if (mask) {
          int ka = kb + ((c >> 1) << 5) + (c & 1) + 8 * lg + 2 * r;
          v = (ka <= qrow) ? v : -1e30f;
        }
        xv[c][r] = v;
        mt = fmaxf(mt, v);
      }
    mt = fmaxf(mt, __shfl_xor(mt, 16));
    mt = fmaxf(mt, __shfl_xor(mt, 32));
    float facm = 1.0f;
    if (!__all(mt <= mrow[t] + 8.0f)) {        // defer-max (T13), log2 units
      float mnew = fmaxf(mrow[t], mt);
      facm = exp2f(mrow[t] - mnew);
      mrow[t] = mnew;
#pragma unroll
      for (int dt = 0; dt < 8; ++dt)
#pragma unroll
        for (int r = 0; r < 4; ++r) acc[t][dt][r] *= facm;
    }
    float rs = 0.f;
    float pv[4][4];
#pragma unroll
    for (int c = 0; c < 4; ++c)
#pragma unroll
      for (int r = 0; r < 4; ++r) {
        float p = exp2f(xv[c][r] - mrow[t]);
        pv[c][r] = p;
        rs += p;
      }
    rs += __shfl_xor(rs, 16);
    rs += __shfl_xor(rs, 32);
    lsum[t] = lsum[t] * facm + rs;
#pragma unroll
    for (int kk = 0; kk < 2; ++kk) {
      union { bf16x8 v8; unsigned u[4]; } uu;
#pragma unroll
      for (int wd = 0; wd < 4; ++wd)
        uu.u[wd] = pack2(pv[2 * kk][wd], pv[2 * kk + 1][wd]);
      pt[kk] = uu.v8;
    }
  };

  const int nst = 2 * qt + 2;
  for (int j = 0; j < nst; ++j) {
    const int kb = j * 64;
    __syncthreads();                        // prev step's LDS reads complete
    {
      const char* kg = kgbase + (size_t)kb * 256;
      const char* vg = vgbase + (size_t)kb * 2;
#pragma unroll
      for (int i = 0; i < 4; ++i) {
        gload_lds16(kg + ksrc[i], (char*)Ks + w * 4096 + i * 1024);
        gload_lds16(vg + vsrc[i], (char*)Vs + w * 4096 + i * 1024);
      }
    }
    __syncthreads();                        // drains gload_lds (vmcnt0) + barrier
    const bool only1 = (j == nst - 1);
    const bool do0 = !only1;
    const bool m0 = (j == nst - 2);
    const bool m1 = only1;
    f32x4 sT0[4], sT1[4];
    __builtin_amdgcn_s_setprio(1);
#pragma unroll
    for (int c = 0; c < 4; ++c) {
      bf16x8 kf[4];
#pragma unroll
      for (int s = 0; s < 4; ++s)
        kf[s] = *reinterpret_cast<const bf16x8*>((char*)Ks + (((c * 16 + lr) * 256 + s * 64 + lg * 16) ^ swz));
      f32x4 t0 = {0.f, 0.f, 0.f, 0.f}, t1 = {0.f, 0.f, 0.f, 0.f};
#pragma unroll
      for (int s = 0; s < 4; ++s) {
        if (do0) t0 = __builtin_amdgcn_mfma_f32_16x16x32_bf16(kf[s], qf[0][s], t0, 0, 0, 0);
        t1 = __builtin_amdgcn_mfma_f32_16x16x32_bf16(kf[s], qf[1][s], t1, 0, 0, 0);
      }
      sT0[c] = t0; sT1[c] = t1;
    }
    __builtin_amdgcn_s_setprio(0);
    bf16x8 pt0[2], pt1[2];
    if (do0) softmax_t(sT0, 0, m0, qr0, kb, pt0);
    softmax_t(sT1, 1, m1, qr1, kb, pt1);
    __builtin_amdgcn_s_setprio(1);
#pragma unroll
    for (int dt = 0; dt < 8; ++dt) {
      bf16x8 v0 = *reinterpret_cast<const bf16x8*>((char*)Vs + (((dt * 16 + lr) * 128 + lg * 16) ^ swz));
      bf16x8 v1 = *reinterpret_cast<const bf16x8*>((char*)Vs + (((dt * 16 + lr) * 128 + 64 + lg * 16) ^ swz));
      if (do0) {
        acc[0][dt] = __builtin_amdgcn_mfma_f32_16x16x32_bf16(v0, pt0[0], acc[0][dt], 0, 0, 0);
        acc[0][dt] = __builtin_amdgcn_mfma_f32_16x16x32_bf16(v1, pt0[1], acc[0][dt], 0, 0, 0);
      }
      acc[1][dt] = __builtin_amdgcn_mfma_f32_16x16x32_bf16(v0, pt1[0], acc[1][dt], 0, 0, 0);
      acc[1][dt] = __builtin_amdgcn_mfma_f32_16x16x32_bf16(v1, pt1[1], acc[1][dt], 0, 0, 0);
    }
    __builtin_amdgcn_s_setprio(0);
  }

#pragma unroll
  for (int t = 0; t < 2; ++t) {
    const int qrow = t ? qr1 : qr0;
    float inv = 1.0f / lsum[t];
#pragma unroll
    for (int dt = 0; dt < 8; ++dt) {
      ushort4 o;
      o.x = f32_to_bf16(acc[t][dt][0] * inv);
      o.y = f32_to_bf16(acc[t][dt][1] * inv);
      o.z = f32_to_bf16(acc[t][dt][2] * inv);
      o.w = f32_to_bf16(acc[t][dt][3] * inv);
      *reinterpret_cast<ushort4*>(obf + ((size_t)(b * 2048 + qrow)) * 2048 + h * 128 + dt * 16 + lg * 4) = o;
    }
  }
}

// ---------------- host launch ----------------
extern "C" void kernel_launch(void* const* d_in, const int* in_sizes, int n_in,
                              void* d_out, int out_size, void* d_ws, size_t ws_size,
                              hipStream_t stream) {
  const float* x  = (const float*)d_in[0];
  const float* fc = (const float*)d_in[1];
  const float* fs = (const float*)d_in[2];
  const float* wq = (const float*)d_in[3];
  const float* wk = (const float*)d_in[4];
  const float* wv = (const float*)d_in[5];
  const float* wo = (const float*)d_in[6];

  float* out    = (float*)d_out;
  float* keys   = out + 8388608;
  float* values = out + 16777216;

  char* ws = (char*)d_ws;
  unsigned short* WQKV = (unsigned short*)(ws + 0);          // 12.6 MB: [wq;wk;wv] (3072 x 2048)
  unsigned short* WO   = (unsigned short*)(ws + 12582912);   // 8 MB
  unsigned short* XBF  = (unsigned short*)(ws + 20971520);   // 16 MB (reused as ATT)
  float*          XQKV = (float*)(ws + 37748736);            // 50.3 MB (4096 x 3072)
  unsigned short* KBF  = (unsigned short*)(ws + 88080384);   // 4 MB
  unsigned short* VTB  = (unsigned short*)(ws + 92274688);   // 4 MB
  unsigned short* ATT  = XBF;                                // alias: XBF dead after projection

  cast2_bf16_kernel<<<8192, 256, 0, stream>>>(wq, WQKV, 1048576, wo, WO);
  cast2_bf16_kernel<<<2048, 256, 0, stream>>>(wk, WQKV + 2048 * 2048, 262144,
                                              wv, WQKV + 2560 * 2048);
  cast_bf16_kernel<<<8192, 256, 0, stream>>>(x, XBF);

  // fused QKV projection: C (4096 x 3072) = XBF * WQKV^T  (256x256 tiles, 192 blocks)
  gemm256_kernel<256><<<dim3(12, 16), 512, 0, stream>>>(XBF, WQKV, XQKV, 4096, 3072, 2048);

  rope_k_kernel<<<4096, 256, 0, stream>>>(XQKV, fc, fs, KBF, keys);
  v_proc_kernel<<<8192, 256, 0, stream>>>(XQKV, VTB, values);

  attn_kernel<<<512, 256, 0, stream>>>(XQKV, fc, fs, KBF, VTB, ATT);

  // output projection (128x256 tiles, 256 blocks -> full fill)
  gemm256_kernel<128><<<dim3(8, 32), 512, 0, stream>>>(ATT, WO, out, 4096, 2048, 2048);
}